// Round 7
// baseline (139.185 us; speedup 1.0000x reference)
//
#include <hip/hip_runtime.h>

// B=64, H=W=32, HW=1024, steps<=256 (freeze break), backtrack 255.
// Outputs: [histories 65536][paths 65536][pred_cost 65536] float32.
// Single fused kernel: 64 blocks (1 per batch) x 256 threads.
//   Phase 1 (all 256 thr): conv1(2->32)+ReLU, conv2(32->1)+sigmoid.
//            pix = p*256 + t (lane-contiguous; x = t&31). x+-1 neighbor taps
//            via DPP wave_shr:1 / wave_shl:1. ROUND-6 BUG FIX: DPP builtins are
//            convergent; putting them inside `cond ? dpp(..) : 0` forces a
//            divergent branch (C++ evaluation rules) -> DPP ran with boundary
//            lanes masked out of EXEC -> reads from inactive lanes returned
//            stale own-values. Fix: DPP calls are unconditional straight-line
//            statements (full EXEC), masking applied to the RESULT via select.
//            Tap values / per-pixel accumulation order bit-identical to round 5
//            (absmax 0.0).
//   Phase 2 (wave 0 only, no barriers): A* steps, byte-identical to round 5
//            (LDS vkey scan + u64 tree + row_shr DPP reduce + register masks +
//            freeze break).
//   Phase 3 (all): backtrack (lane 0) + output writes. Unchanged.

#define HW 1024

// DPP wave-64 max-reduce step on a u64 key (hi=value bits, lo=1023-cell).
// row_shr accumulates into lanes 15/31/47/63; bcast15/31 -> lane 63 holds max.
#define DPP_MAX64(key, ctrl) do {                                              \
    unsigned int _lo = (unsigned int)(key);                                    \
    unsigned int _hi = (unsigned int)((key) >> 32);                            \
    unsigned int _slo = (unsigned int)__builtin_amdgcn_update_dpp(             \
        (int)_lo, (int)_lo, (ctrl), 0xf, 0xf, false);                          \
    unsigned int _shi = (unsigned int)__builtin_amdgcn_update_dpp(             \
        (int)_hi, (int)_hi, (ctrl), 0xf, 0xf, false);                          \
    unsigned long long _o = ((unsigned long long)_shi << 32) | _slo;           \
    if (_o > (key)) (key) = _o;                                                \
} while (0)

// lane i <- lane i-1 (x-1 neighbor). shr moves data toward higher lanes
// (empirical: rounds 2/3). MUST be called unconditionally (convergent).
__device__ __forceinline__ float dpp_shr1(float v) {
  int i = __float_as_int(v);
  return __int_as_float(__builtin_amdgcn_update_dpp(i, i, 0x138, 0xf, 0xf, false));
}
// lane i <- lane i+1 (x+1 neighbor). MUST be called unconditionally.
__device__ __forceinline__ float dpp_shl1(float v) {
  int i = __float_as_int(v);
  return __int_as_float(__builtin_amdgcn_update_dpp(i, i, 0x130, 0xf, 0xf, false));
}

__global__ __launch_bounds__(256) void fused_nastar(
    const float* __restrict__ maps, const float* __restrict__ start,
    const float* __restrict__ goal, const float* __restrict__ w1,
    const float* __restrict__ b1, const float* __restrict__ w2,
    const float* __restrict__ b2, float* __restrict__ out_hist,
    float* __restrict__ out_path, float* __restrict__ out_cost) {
  __shared__ float hid[8][HW];            // 32 KB
  __shared__ float c_l[HW];               // 4 KB: cost
  __shared__ float g_l[HW];               // 4 KB: g
  __shared__ float h_l[HW];               // 4 KB: heuristic + cost (h4)
  __shared__ unsigned int vkey[HW];       // 4 KB: f32 bits of v (0 if closed)
  __shared__ unsigned short par[HW];      // 2 KB
  __shared__ unsigned char path_sh[HW];   // 1 KB
  __shared__ unsigned int hist_lds[64];   // 256 B
  // ~51.3 KB

  const int t = threadIdx.x;
  const int b = blockIdx.x;
  const float C_INV = 0.17677669529663687f;  // float32(1/sqrt(32))

  const float* m_p = maps  + b * HW;
  const float* s_p = start + b * HW;
  const float* g_p = goal  + b * HW;

  // ---------------- Phase 1: encoder (DPP neighbor taps, full-EXEC) --------
  const int xl = t & 31;                  // own x (lane within row-of-32)
  const bool hasL = (xl > 0), hasR = (xl < 31);
  float win0[4][9], win1[4][9];
  #pragma unroll
  for (int p = 0; p < 4; ++p) {
    int pix = p * 256 + t;
    int y = pix >> 5;
    #pragma unroll
    for (int rr = 0; rr < 3; ++rr) {
      int yy = y + rr - 1;
      bool ok = (yy >= 0) && (yy <= 31);
      int q = ok ? (yy * 32 + xl) : xl;
      float mv  = m_p[q];
      float sgv = s_p[q] + g_p[q];
      float c0 = ok ? mv : 0.0f;          // center tap (yy-masked)
      float c1 = ok ? sgv : 0.0f;
      // DPP unconditional (full EXEC); mask the RESULT only.
      float l0 = dpp_shr1(c0), l1 = dpp_shr1(c1);
      float r0 = dpp_shl1(c0), r1 = dpp_shl1(c1);
      win0[p][rr * 3 + 1] = c0;
      win1[p][rr * 3 + 1] = c1;
      win0[p][rr * 3 + 0] = hasL ? l0 : 0.0f;   // x-1
      win1[p][rr * 3 + 0] = hasL ? l1 : 0.0f;
      win0[p][rr * 3 + 2] = hasR ? r0 : 0.0f;   // x+1
      win1[p][rr * 3 + 2] = hasR ? r1 : 0.0f;
    }
  }

  float acc2[4] = {b2[0], b2[0], b2[0], b2[0]};
  for (int grp = 0; grp < 4; ++grp) {
    // conv1 for oc in [8*grp, 8*grp+8): windows already in registers
    #pragma unroll
    for (int p = 0; p < 4; ++p) {
      int pix = p * 256 + t;
      #pragma unroll
      for (int ocl = 0; ocl < 8; ++ocl) {
        int oc = grp * 8 + ocl;
        const float* w = w1 + oc * 18;
        float acc = b1[oc];
        #pragma unroll
        for (int k = 0; k < 9; ++k) {
          acc += win0[p][k] * w[k];       // same per-pixel op order as round 1
          acc += win1[p][k] * w[9 + k];
        }
        hid[ocl][pix] = fmaxf(acc, 0.0f);
      }
    }
    __syncthreads();
    // conv2 partial: own-column LDS read + DPP for x+-1 (ky-major, kx 0,1,2)
    #pragma unroll
    for (int p = 0; p < 4; ++p) {
      int pix = p * 256 + t;
      int y = pix >> 5;
      float a = acc2[p];
      #pragma unroll
      for (int ocl = 0; ocl < 8; ++ocl) {
        int ic = grp * 8 + ocl;
        const float* w = w2 + ic * 9;
        #pragma unroll
        for (int rr = 0; rr < 3; ++rr) {
          int yy = y + rr - 1;
          bool okc = (yy >= 0) && (yy <= 31);
          int q = okc ? (yy * 32 + xl) : xl;
          float hv = hid[ocl][q];
          float cm = okc ? hv : 0.0f;
          float sL = dpp_shr1(cm);        // unconditional (full EXEC)
          float sR = dpp_shl1(cm);
          float lv = hasL ? sL : 0.0f;
          float rv = hasR ? sR : 0.0f;
          a += lv * w[rr * 3 + 0];
          a += cm * w[rr * 3 + 1];
          a += rv * w[rr * 3 + 2];
        }
      }
      acc2[p] = a;
    }
    __syncthreads();
  }
  #pragma unroll
  for (int p = 0; p < 4; ++p) {
    int pix = p * 256 + t;
    float c = 1.0f / (1.0f + expf(-acc2[p]));
    c_l[pix] = c;
    out_cost[b * HW + pix] = c;          // stride-1 across lanes: coalesced
  }
  __syncthreads();

  // ---------------- Phase 2: A* (wave 0, LDS scan + register masks) --------
  if (t < 64) {
    const int lane = t;
    reinterpret_cast<int4*>(path_sh)[lane] = make_int4(0, 0, 0, 0);
    // goal via ballot (one-hot)
    int myg = -1;
    #pragma unroll
    for (int j = 0; j < 16; ++j) {
      int cell = j * 64 + lane;
      if (g_p[cell] > 0.5f) myg = cell;
    }
    unsigned long long gm = __ballot(myg >= 0);
    int src_lane = (int)__ffsll(gm) - 1;
    const int goal_idx = __shfl(myg, src_lane, 64);
    const int gy = goal_idx >> 5, gx = goal_idx & 31;

    unsigned int open_m = 0, hist_m = 0, obs_m = 0;
    #pragma unroll
    for (int j = 0; j < 16; ++j) {
      int cell = j * 64 + lane;
      int y = cell >> 5, x = cell & 31;
      float cst = c_l[cell];
      int dy = y - gy; dy = dy < 0 ? -dy : dy;
      int dx = x - gx; dx = dx < 0 ? -dx : dx;
      float e = sqrtf((float)(dy * dy + dx * dx));
      float heur = __fadd_rn((float)(dy + dx), __fmul_rn(0.001f, e));
      float hc = __fadd_rn(heur, cst);       // h4 = heuristic + cost
      h_l[cell] = hc;
      g_l[cell] = 0.0f;
      bool isobs = (m_p[cell] != 0.0f);
      bool isst  = (s_p[cell] > 0.5f);
      if (isobs) obs_m  |= 1u << j;
      if (isst)  open_m |= 1u << j;
      float f = 0.5f * (0.0f + hc);
      float ex = expf(__fmul_rn(-f, C_INV));
      vkey[cell] = isst ? __float_as_uint(ex) : 0u;
      par[cell] = (unsigned short)goal_idx;
    }

    const int x = lane & 31, half = lane >> 5;
    const unsigned int lowbase = 1023u - (unsigned)lane;  // lo = lowbase - 64j

    for (int step = 0; step < 256; ++step) {
      // LDS scan (stride-64 words = conflict-free) + local 16->1 max tree
      unsigned long long k[16];
      #pragma unroll
      for (int j = 0; j < 16; ++j) {
        unsigned int v = vkey[j * 64 + lane];
        k[j] = ((unsigned long long)v << 32) | (lowbase - 64u * (unsigned)j);
      }
      #pragma unroll
      for (int s = 8; s >= 1; s >>= 1) {
        #pragma unroll
        for (int i = 0; i < s; ++i)
          if (k[i + s] > k[i]) k[i] = k[i + s];
      }
      unsigned long long key = k[0];
      DPP_MAX64(key, 0x111);  // row_shr:1
      DPP_MAX64(key, 0x112);  // row_shr:2
      DPP_MAX64(key, 0x114);  // row_shr:4
      DPP_MAX64(key, 0x118);  // row_shr:8
      DPP_MAX64(key, 0x142);  // row_bcast:15
      DPP_MAX64(key, 0x143);  // row_bcast:31
      unsigned int klo =
          (unsigned int)__builtin_amdgcn_readlane((int)(unsigned int)key, 63);
      const int sel = __builtin_amdgcn_readfirstlane(1023 - (int)klo);
      const int jsel = sel >> 6, owner = sel & 63;
      const int ys = sel >> 5, xs = sel & 31;
      const bool unsolved = (sel != goal_idx);

      // candidate geometry (relax lane == owner lane; round-4 proven)
      int dxs = x - xs; int adx = dxs < 0 ? -dxs : dxs;
      const bool act = (adx <= 1);
      const bool samep = (((ys ^ half) & 1) == 0);
      const int yA = samep ? ys : (ys - 1);
      const bool vAv = act && (samep ? (adx >= 1) : (yA >= 0));
      const int yB = ys + 1;
      const bool vBv = act && (!samep) && (yB <= 31);
      const int cA = vAv ? (yA * 32 + x) : 0;
      const int cB = vBv ? (yB * 32 + x) : 0;

      // one LDS latency window: uniform sel reads + stride-1 candidate reads
      float gs = g_l[sel];
      float cs = c_l[sel];
      float gA = g_l[cA], hA = h_l[cA];
      float gB = g_l[cB], hB = h_l[cB];

      const float gsum = gs + cs;            // g2 value (exact, as reference)
      const int vjA = yA >> 1;               // candidate j (per-half value)
      const int jB  = yB >> 1;

      bool obA = (obs_m  >> (vjA & 15)) & 1;
      bool opA = (open_m >> (vjA & 15)) & 1;
      bool hiA = (hist_m >> (vjA & 15)) & 1;
      bool obB = (obs_m  >> (jB  & 15)) & 1;
      bool opB = (open_m >> (jB  & 15)) & 1;
      bool hiB = (hist_m >> (jB  & 15)) & 1;

      const bool idxA = vAv && obA && ((!opA && !hiA) || (opA && (gA > gsum)));
      const bool idxB = vBv && obB && ((!opB && !hiB) || (opB && (gB > gsum)));
      const bool ownerlane = (lane == owner);
      const bool closeU = unsolved && ownerlane;

      // change detection (pre-update bits)
      const bool histnew = ownerlane && !((hist_m >> (jsel & 15)) & 1);
      const bool opencl  = closeU && ((open_m >> (jsel & 15)) & 1);

      // mask updates
      hist_m |= ownerlane ? (1u << (jsel & 15)) : 0u;
      unsigned int clr = closeU ? (1u << (jsel & 15)) : 0u;
      unsigned int aA  = idxA ? (1u << (vjA & 15)) : 0u;
      unsigned int aB  = idxB ? (1u << (jB  & 15)) : 0u;
      open_m = (open_m & ~clr) | aA | aB;

      // LDS updates (exec-masked)
      if (closeU) vkey[sel] = 0u;
      float fA = 0.5f * (gsum + hA);
      unsigned int nvA = __float_as_uint(expf(__fmul_rn(-fA, C_INV)));
      float fB = 0.5f * (gsum + hB);
      unsigned int nvB = __float_as_uint(expf(__fmul_rn(-fB, C_INV)));
      if (idxA) { g_l[cA] = gsum; vkey[cA] = nvA; par[cA] = (unsigned short)sel; }
      if (idxB) { g_l[cB] = gsum; vkey[cB] = nvB; par[cB] = (unsigned short)sel; }

      // freeze: nothing changed => fixed point => all remaining steps no-ops
      unsigned long long anych = __ballot(idxA || idxB || histnew || opencl);
      if (anych == 0ull) break;
    }

    hist_lds[lane] = hist_m;

    // backtrack (parent table static; revisit => cycle => exact early exit)
    if (lane == 0) {
      path_sh[goal_idx] = 1;
      int loc = par[goal_idx];
      for (int i = 0; i < 255; ++i) {
        if (path_sh[loc]) break;
        path_sh[loc] = 1;
        loc = par[loc];
      }
    }
  }
  __syncthreads();

  // ---------------- Phase 3: outputs ----------------
  const int base = t * 4;
  float hv[4], pv[4];
  #pragma unroll
  for (int p = 0; p < 4; ++p) {
    int cell = base + p;
    hv[p] = (float)((hist_lds[cell & 63] >> (cell >> 6)) & 1);
    pv[p] = (float)path_sh[cell];
  }
  *reinterpret_cast<float4*>(out_hist + b * HW + base) =
      make_float4(hv[0], hv[1], hv[2], hv[3]);
  *reinterpret_cast<float4*>(out_path + b * HW + base) =
      make_float4(pv[0], pv[1], pv[2], pv[3]);
}

extern "C" void kernel_launch(void* const* d_in, const int* in_sizes, int n_in,
                              void* d_out, int out_size, void* d_ws, size_t ws_size,
                              hipStream_t stream) {
  (void)in_sizes; (void)n_in; (void)d_ws; (void)ws_size; (void)out_size;
  const float* maps  = (const float*)d_in[0];
  const float* start = (const float*)d_in[1];
  const float* goal  = (const float*)d_in[2];
  const float* w1    = (const float*)d_in[3];
  const float* b1    = (const float*)d_in[4];
  const float* w2    = (const float*)d_in[5];
  const float* b2    = (const float*)d_in[6];

  float* out      = (float*)d_out;
  float* out_hist = out;
  float* out_path = out + 64 * HW;
  float* out_cost = out + 128 * HW;

  fused_nastar<<<64, 256, 0, stream>>>(maps, start, goal, w1, b1, w2, b2,
                                       out_hist, out_path, out_cost);
}

// Round 8
// 138.728 us; speedup vs baseline: 1.0033x; 1.0033x over previous
//
#include <hip/hip_runtime.h>

// B=64, H=W=32, HW=1024, steps<=256 (freeze break), backtrack 255.
// Outputs: [histories 65536][paths 65536][pred_cost 65536] float32.
// Single fused kernel: 64 blocks (1 per batch) x 256 threads.
//   Phase 1: encoder, unchanged from round 7 (absmax 0.0): DPP neighbor taps,
//            full-EXEC DPP calls, result-masking only.
//   Phase 2 (wave 0, no barriers): A* steps. Round-8 changes (all exact):
//            (a) (g,h) packed as float2 gh[] -> candidate reads are 2x
//                ds_read_b64 (lane-stride-2 = 2-way = free);
//            (b) software-pipelined vkey scan: next step's 16 reads issue at
//                the END of the body (after relax writes), overlapping the
//                drain with loop-back + key build; vkey[sel] cleared EARLY;
//            (c) wave-uniform skip of the expf/relax-write block when
//                ballot(idxA||idxB)==0 (skipped work is a no-op).
//            Arithmetic expressions and order bit-identical to round 5/7.
//   Phase 3: backtrack (lane 0) + output writes. Unchanged.

#define HW 1024

// DPP wave-64 max-reduce step on a u64 key (hi=value bits, lo=1023-cell).
// row_shr accumulates into lanes 15/31/47/63; bcast15/31 -> lane 63 holds max.
#define DPP_MAX64(key, ctrl) do {                                              \
    unsigned int _lo = (unsigned int)(key);                                    \
    unsigned int _hi = (unsigned int)((key) >> 32);                            \
    unsigned int _slo = (unsigned int)__builtin_amdgcn_update_dpp(             \
        (int)_lo, (int)_lo, (ctrl), 0xf, 0xf, false);                          \
    unsigned int _shi = (unsigned int)__builtin_amdgcn_update_dpp(             \
        (int)_hi, (int)_hi, (ctrl), 0xf, 0xf, false);                          \
    unsigned long long _o = ((unsigned long long)_shi << 32) | _slo;           \
    if (_o > (key)) (key) = _o;                                                \
} while (0)

// lane i <- lane i-1 (x-1). MUST be called unconditionally (convergent).
__device__ __forceinline__ float dpp_shr1(float v) {
  int i = __float_as_int(v);
  return __int_as_float(__builtin_amdgcn_update_dpp(i, i, 0x138, 0xf, 0xf, false));
}
// lane i <- lane i+1 (x+1). MUST be called unconditionally.
__device__ __forceinline__ float dpp_shl1(float v) {
  int i = __float_as_int(v);
  return __int_as_float(__builtin_amdgcn_update_dpp(i, i, 0x130, 0xf, 0xf, false));
}

__global__ __launch_bounds__(256) void fused_nastar(
    const float* __restrict__ maps, const float* __restrict__ start,
    const float* __restrict__ goal, const float* __restrict__ w1,
    const float* __restrict__ b1, const float* __restrict__ w2,
    const float* __restrict__ b2, float* __restrict__ out_hist,
    float* __restrict__ out_path, float* __restrict__ out_cost) {
  __shared__ float hid[8][HW];            // 32 KB
  __shared__ float c_l[HW];               // 4 KB: cost
  __shared__ float2 gh[HW];               // 8 KB: {g, heuristic+cost}
  __shared__ unsigned int vkey[HW];       // 4 KB: f32 bits of v (0 if closed)
  __shared__ unsigned short par[HW];      // 2 KB
  __shared__ unsigned char path_sh[HW];   // 1 KB
  __shared__ unsigned int hist_lds[64];   // 256 B
  // ~51.3 KB

  const int t = threadIdx.x;
  const int b = blockIdx.x;
  const float C_INV = 0.17677669529663687f;  // float32(1/sqrt(32))

  const float* m_p = maps  + b * HW;
  const float* s_p = start + b * HW;
  const float* g_p = goal  + b * HW;

  // ---------------- Phase 1: encoder (round-7, bit-exact) ------------------
  const int xl = t & 31;
  const bool hasL = (xl > 0), hasR = (xl < 31);
  float win0[4][9], win1[4][9];
  #pragma unroll
  for (int p = 0; p < 4; ++p) {
    int pix = p * 256 + t;
    int y = pix >> 5;
    #pragma unroll
    for (int rr = 0; rr < 3; ++rr) {
      int yy = y + rr - 1;
      bool ok = (yy >= 0) && (yy <= 31);
      int q = ok ? (yy * 32 + xl) : xl;
      float mv  = m_p[q];
      float sgv = s_p[q] + g_p[q];
      float c0 = ok ? mv : 0.0f;
      float c1 = ok ? sgv : 0.0f;
      float l0 = dpp_shr1(c0), l1 = dpp_shr1(c1);
      float r0 = dpp_shl1(c0), r1 = dpp_shl1(c1);
      win0[p][rr * 3 + 1] = c0;
      win1[p][rr * 3 + 1] = c1;
      win0[p][rr * 3 + 0] = hasL ? l0 : 0.0f;
      win1[p][rr * 3 + 0] = hasL ? l1 : 0.0f;
      win0[p][rr * 3 + 2] = hasR ? r0 : 0.0f;
      win1[p][rr * 3 + 2] = hasR ? r1 : 0.0f;
    }
  }

  float acc2[4] = {b2[0], b2[0], b2[0], b2[0]};
  for (int grp = 0; grp < 4; ++grp) {
    #pragma unroll
    for (int p = 0; p < 4; ++p) {
      int pix = p * 256 + t;
      #pragma unroll
      for (int ocl = 0; ocl < 8; ++ocl) {
        int oc = grp * 8 + ocl;
        const float* w = w1 + oc * 18;
        float acc = b1[oc];
        #pragma unroll
        for (int k = 0; k < 9; ++k) {
          acc += win0[p][k] * w[k];
          acc += win1[p][k] * w[9 + k];
        }
        hid[ocl][pix] = fmaxf(acc, 0.0f);
      }
    }
    __syncthreads();
    #pragma unroll
    for (int p = 0; p < 4; ++p) {
      int pix = p * 256 + t;
      int y = pix >> 5;
      float a = acc2[p];
      #pragma unroll
      for (int ocl = 0; ocl < 8; ++ocl) {
        int ic = grp * 8 + ocl;
        const float* w = w2 + ic * 9;
        #pragma unroll
        for (int rr = 0; rr < 3; ++rr) {
          int yy = y + rr - 1;
          bool okc = (yy >= 0) && (yy <= 31);
          int q = okc ? (yy * 32 + xl) : xl;
          float hv = hid[ocl][q];
          float cm = okc ? hv : 0.0f;
          float sL = dpp_shr1(cm);
          float sR = dpp_shl1(cm);
          float lv = hasL ? sL : 0.0f;
          float rv = hasR ? sR : 0.0f;
          a += lv * w[rr * 3 + 0];
          a += cm * w[rr * 3 + 1];
          a += rv * w[rr * 3 + 2];
        }
      }
      acc2[p] = a;
    }
    __syncthreads();
  }
  #pragma unroll
  for (int p = 0; p < 4; ++p) {
    int pix = p * 256 + t;
    float c = 1.0f / (1.0f + expf(-acc2[p]));
    c_l[pix] = c;
    out_cost[b * HW + pix] = c;
  }
  __syncthreads();

  // ---------------- Phase 2: A* (wave 0, pipelined scan) -------------------
  if (t < 64) {
    const int lane = t;
    reinterpret_cast<int4*>(path_sh)[lane] = make_int4(0, 0, 0, 0);
    int myg = -1;
    #pragma unroll
    for (int j = 0; j < 16; ++j) {
      int cell = j * 64 + lane;
      if (g_p[cell] > 0.5f) myg = cell;
    }
    unsigned long long gm = __ballot(myg >= 0);
    int src_lane = (int)__ffsll(gm) - 1;
    const int goal_idx = __shfl(myg, src_lane, 64);
    const int gy = goal_idx >> 5, gx = goal_idx & 31;

    unsigned int open_m = 0, hist_m = 0, obs_m = 0;
    #pragma unroll
    for (int j = 0; j < 16; ++j) {
      int cell = j * 64 + lane;
      int y = cell >> 5, x = cell & 31;
      float cst = c_l[cell];
      int dy = y - gy; dy = dy < 0 ? -dy : dy;
      int dx = x - gx; dx = dx < 0 ? -dx : dx;
      float e = sqrtf((float)(dy * dy + dx * dx));
      float heur = __fadd_rn((float)(dy + dx), __fmul_rn(0.001f, e));
      float hc = __fadd_rn(heur, cst);       // h4 = heuristic + cost
      gh[cell] = make_float2(0.0f, hc);
      bool isobs = (m_p[cell] != 0.0f);
      bool isst  = (s_p[cell] > 0.5f);
      if (isobs) obs_m  |= 1u << j;
      if (isst)  open_m |= 1u << j;
      float f = 0.5f * (0.0f + hc);
      float ex = expf(__fmul_rn(-f, C_INV));
      vkey[cell] = isst ? __float_as_uint(ex) : 0u;
      par[cell] = (unsigned short)goal_idx;
    }

    const int x = lane & 31, half = lane >> 5;
    const unsigned int lowbase = 1023u - (unsigned)lane;  // lo = lowbase - 64j

    // prologue scan (software pipeline)
    unsigned int sv[16];
    #pragma unroll
    for (int j = 0; j < 16; ++j) sv[j] = vkey[j * 64 + lane];

    for (int step = 0; step < 256; ++step) {
      // local 16->1 max tree on u64 keys (from pipelined scan regs)
      unsigned long long k[16];
      #pragma unroll
      for (int j = 0; j < 16; ++j)
        k[j] = ((unsigned long long)sv[j] << 32) | (lowbase - 64u * (unsigned)j);
      #pragma unroll
      for (int s = 8; s >= 1; s >>= 1) {
        #pragma unroll
        for (int i = 0; i < s; ++i)
          if (k[i + s] > k[i]) k[i] = k[i + s];
      }
      unsigned long long key = k[0];
      DPP_MAX64(key, 0x111);  // row_shr:1
      DPP_MAX64(key, 0x112);  // row_shr:2
      DPP_MAX64(key, 0x114);  // row_shr:4
      DPP_MAX64(key, 0x118);  // row_shr:8
      DPP_MAX64(key, 0x142);  // row_bcast:15
      DPP_MAX64(key, 0x143);  // row_bcast:31
      unsigned int klo =
          (unsigned int)__builtin_amdgcn_readlane((int)(unsigned int)key, 63);
      const int sel = __builtin_amdgcn_readfirstlane(1023 - (int)klo);
      const int jsel = sel >> 6, owner = sel & 63;
      const int ys = sel >> 5, xs = sel & 31;
      const bool unsolved = (sel != goal_idx);
      const bool ownerlane = (lane == owner);
      const bool closeU = unsolved && ownerlane;

      // EARLY clear (feeds next scan; no dependence on window-2)
      if (closeU) vkey[sel] = 0u;

      // candidate geometry (relax lane == owner lane)
      int dxs = x - xs; int adx = dxs < 0 ? -dxs : dxs;
      const bool act = (adx <= 1);
      const bool samep = (((ys ^ half) & 1) == 0);
      const int yA = samep ? ys : (ys - 1);
      const bool vAv = act && (samep ? (adx >= 1) : (yA >= 0));
      const int yB = ys + 1;
      const bool vBv = act && (!samep) && (yB <= 31);
      const int cA = vAv ? (yA * 32 + x) : 0;
      const int cB = vBv ? (yB * 32 + x) : 0;

      // window-2 LDS reads (uniform sel + 2x b64 candidates)
      float gs = gh[sel].x;
      float cs = c_l[sel];
      float2 rA = gh[cA];
      float2 rB = gh[cB];

      // mask logic overlapped with the drain
      const int vjA = yA >> 1;
      const int jB  = yB >> 1;
      bool obA = (obs_m  >> (vjA & 15)) & 1;
      bool opA = (open_m >> (vjA & 15)) & 1;
      bool hiA = (hist_m >> (vjA & 15)) & 1;
      bool obB = (obs_m  >> (jB  & 15)) & 1;
      bool opB = (open_m >> (jB  & 15)) & 1;
      bool hiB = (hist_m >> (jB  & 15)) & 1;
      const bool histnew = ownerlane && !((hist_m >> (jsel & 15)) & 1);
      const bool opencl  = closeU && ((open_m >> (jsel & 15)) & 1);
      hist_m |= ownerlane ? (1u << (jsel & 15)) : 0u;

      const float gsum = gs + cs;            // g2 value (exact, as reference)
      const bool idxA = vAv && obA && ((!opA && !hiA) || (opA && (rA.x > gsum)));
      const bool idxB = vBv && obB && ((!opB && !hiB) || (opB && (rB.x > gsum)));

      unsigned long long bal_all = __ballot(idxA || idxB || histnew || opencl);
      unsigned long long bal_rx  = __ballot(idxA || idxB);

      unsigned int clr = closeU ? (1u << (jsel & 15)) : 0u;
      unsigned int aA  = idxA ? (1u << (vjA & 15)) : 0u;
      unsigned int aB  = idxB ? (1u << (jB  & 15)) : 0u;
      open_m = (open_m & ~clr) | aA | aB;

      // relax/expf/write block: wave-uniform skip when no relax fires
      if (bal_rx != 0ull) {
        float fA = 0.5f * (gsum + rA.y);
        unsigned int nvA = __float_as_uint(expf(__fmul_rn(-fA, C_INV)));
        float fB = 0.5f * (gsum + rB.y);
        unsigned int nvB = __float_as_uint(expf(__fmul_rn(-fB, C_INV)));
        if (idxA) { gh[cA].x = gsum; vkey[cA] = nvA; par[cA] = (unsigned short)sel; }
        if (idxB) { gh[cB].x = gsum; vkey[cB] = nvB; par[cB] = (unsigned short)sel; }
      }

      // freeze: nothing changed => fixed point => remaining steps are no-ops
      if (bal_all == 0ull) break;

      // pipelined scan for the NEXT step (after all vkey writes this step)
      #pragma unroll
      for (int j = 0; j < 16; ++j) sv[j] = vkey[j * 64 + lane];
    }

    hist_lds[lane] = hist_m;

    // backtrack (parent table static; revisit => cycle => exact early exit)
    if (lane == 0) {
      path_sh[goal_idx] = 1;
      int loc = par[goal_idx];
      for (int i = 0; i < 255; ++i) {
        if (path_sh[loc]) break;
        path_sh[loc] = 1;
        loc = par[loc];
      }
    }
  }
  __syncthreads();

  // ---------------- Phase 3: outputs ----------------
  const int base = t * 4;
  float hv[4], pv[4];
  #pragma unroll
  for (int p = 0; p < 4; ++p) {
    int cell = base + p;
    hv[p] = (float)((hist_lds[cell & 63] >> (cell >> 6)) & 1);
    pv[p] = (float)path_sh[cell];
  }
  *reinterpret_cast<float4*>(out_hist + b * HW + base) =
      make_float4(hv[0], hv[1], hv[2], hv[3]);
  *reinterpret_cast<float4*>(out_path + b * HW + base) =
      make_float4(pv[0], pv[1], pv[2], pv[3]);
}

extern "C" void kernel_launch(void* const* d_in, const int* in_sizes, int n_in,
                              void* d_out, int out_size, void* d_ws, size_t ws_size,
                              hipStream_t stream) {
  (void)in_sizes; (void)n_in; (void)d_ws; (void)ws_size; (void)out_size;
  const float* maps  = (const float*)d_in[0];
  const float* start = (const float*)d_in[1];
  const float* goal  = (const float*)d_in[2];
  const float* w1    = (const float*)d_in[3];
  const float* b1    = (const float*)d_in[4];
  const float* w2    = (const float*)d_in[5];
  const float* b2    = (const float*)d_in[6];

  float* out      = (float*)d_out;
  float* out_hist = out;
  float* out_path = out + 64 * HW;
  float* out_cost = out + 128 * HW;

  fused_nastar<<<64, 256, 0, stream>>>(maps, start, goal, w1, b1, w2, b2,
                                       out_hist, out_path, out_cost);
}